// Round 4
// baseline (112.735 us; speedup 1.0000x reference)
//
#include <hip/hip_runtime.h>
#include <math.h>

// Exact-enough GELU (tanh form, max dev ~3e-4 from erf form; threshold 0.104),
// fp32 -> fp32, memory-bound elementwise. n = 4*4096*4096 = 67,108,864.
// Round 4: 4x unrolled grid-stride loop -> 4 independent loads in flight per
// wave (MLP), nt loads/stores to skip cache pollution.

typedef float f32x4 __attribute__((ext_vector_type(4)));

__device__ __forceinline__ float gelu_fast(float v) {
    const float A = 2.30220771796f;    // 2*log2(e)*sqrt(2/pi)
    const float B = 0.102943213f;      // A * 0.044715
    float x2 = v * v;
    float p = fmaf(x2, B, A);
    float arg = v * p;
    // clamp defensively against exp2 overflow -> inf*rcp -> NaN
    arg = fminf(fmaxf(arg, -126.0f), 126.0f);
    float u = __builtin_amdgcn_exp2f(arg);
    float r = __builtin_amdgcn_rcpf(u + 1.0f);
    return v * u * r;
}

__device__ __forceinline__ f32x4 gelu4(f32x4 v) {
    f32x4 r;
    r.x = gelu_fast(v.x);
    r.y = gelu_fast(v.y);
    r.z = gelu_fast(v.z);
    r.w = gelu_fast(v.w);
    return r;
}

__global__ void __launch_bounds__(256) gelu_f32_kernel(
    const f32x4* __restrict__ x, f32x4* __restrict__ out, int n4) {
    int idx = blockIdx.x * blockDim.x + threadIdx.x;
    int stride = gridDim.x * blockDim.x;
    int i = idx;
    // Main loop: 4 independent loads before any use -> 4x MLP per wave.
    for (; i + 3 * stride < n4; i += 4 * stride) {
        f32x4 v0 = __builtin_nontemporal_load(&x[i]);
        f32x4 v1 = __builtin_nontemporal_load(&x[i + stride]);
        f32x4 v2 = __builtin_nontemporal_load(&x[i + 2 * stride]);
        f32x4 v3 = __builtin_nontemporal_load(&x[i + 3 * stride]);
        f32x4 r0 = gelu4(v0);
        f32x4 r1 = gelu4(v1);
        f32x4 r2 = gelu4(v2);
        f32x4 r3 = gelu4(v3);
        __builtin_nontemporal_store(r0, &out[i]);
        __builtin_nontemporal_store(r1, &out[i + stride]);
        __builtin_nontemporal_store(r2, &out[i + 2 * stride]);
        __builtin_nontemporal_store(r3, &out[i + 3 * stride]);
    }
    // Remainder (dead for n4 = 32*stride, kept for generality).
    for (; i < n4; i += stride) {
        f32x4 v = __builtin_nontemporal_load(&x[i]);
        __builtin_nontemporal_store(gelu4(v), &out[i]);
    }
}

// Scalar tail kernel (defensive; n is divisible by 4 for this problem).
__global__ void gelu_f32_tail_kernel(
    const float* __restrict__ x, float* __restrict__ out, int start, int n) {
    int i = start + blockIdx.x * blockDim.x + threadIdx.x;
    if (i < n) {
        out[i] = gelu_fast(x[i]);
    }
}

extern "C" void kernel_launch(void* const* d_in, const int* in_sizes, int n_in,
                              void* d_out, int out_size, void* d_ws, size_t ws_size,
                              hipStream_t stream) {
    const float* x = (const float*)d_in[0];
    float* out = (float*)d_out;
    int n = in_sizes[0];
    int n4 = n / 4;

    const int block = 256;
    int grid = (n4 + block - 1) / block;
    if (grid > 2048) grid = 2048;  // grid-stride beyond this
    if (grid > 0) {
        gelu_f32_kernel<<<grid, block, 0, stream>>>(
            (const f32x4*)x, (f32x4*)out, n4);
    }

    int tail_start = n4 * 4;
    int tail = n - tail_start;
    if (tail > 0) {
        gelu_f32_tail_kernel<<<1, 64, 0, stream>>>(x, out, tail_start, n);
    }
}

// Round 5
// 85.737 us; speedup vs baseline: 1.3149x; 1.3149x over previous
//
#include <hip/hip_runtime.h>
#include <math.h>

// Exact-enough GELU (tanh form, max dev ~3e-4 from erf form; threshold 0.104),
// fp32 -> fp32, memory-bound elementwise. n = 4*4096*4096 = 67,108,864.
// Round 5: exact grid, one float4 per thread, no loop. Blocks dispatch in
// ~issue order -> the active HBM window slides contiguously (DRAM-friendly),
// unlike persistent grid-stride blocks jumping 8MB per iteration.

typedef float f32x4 __attribute__((ext_vector_type(4)));

__device__ __forceinline__ float gelu_fast(float v) {
    const float A = 2.30220771796f;    // 2*log2(e)*sqrt(2/pi)
    const float B = 0.102943213f;      // A * 0.044715
    float x2 = v * v;
    float p = fmaf(x2, B, A);
    float arg = v * p;
    // clamp defensively against exp2 overflow -> inf*rcp -> NaN
    arg = fminf(fmaxf(arg, -126.0f), 126.0f);
    float u = __builtin_amdgcn_exp2f(arg);
    float r = __builtin_amdgcn_rcpf(u + 1.0f);
    return v * u * r;
}

__global__ void __launch_bounds__(256) gelu_f32_kernel(
    const f32x4* __restrict__ x, f32x4* __restrict__ out, int n4) {
    int i = blockIdx.x * blockDim.x + threadIdx.x;
    if (i < n4) {
        f32x4 v = __builtin_nontemporal_load(&x[i]);
        f32x4 r;
        r.x = gelu_fast(v.x);
        r.y = gelu_fast(v.y);
        r.z = gelu_fast(v.z);
        r.w = gelu_fast(v.w);
        __builtin_nontemporal_store(r, &out[i]);
    }
}

// Scalar tail kernel (defensive; n is divisible by 4 for this problem).
__global__ void gelu_f32_tail_kernel(
    const float* __restrict__ x, float* __restrict__ out, int start, int n) {
    int i = start + blockIdx.x * blockDim.x + threadIdx.x;
    if (i < n) {
        out[i] = gelu_fast(x[i]);
    }
}

extern "C" void kernel_launch(void* const* d_in, const int* in_sizes, int n_in,
                              void* d_out, int out_size, void* d_ws, size_t ws_size,
                              hipStream_t stream) {
    const float* x = (const float*)d_in[0];
    float* out = (float*)d_out;
    int n = in_sizes[0];
    int n4 = n / 4;

    const int block = 256;
    int grid = (n4 + block - 1) / block;  // 65536 for this problem
    if (grid > 0) {
        gelu_f32_kernel<<<grid, block, 0, stream>>>(
            (const f32x4*)x, (f32x4*)out, n4);
    }

    int tail_start = n4 * 4;
    int tail = n - tail_start;
    if (tail > 0) {
        gelu_f32_tail_kernel<<<1, 64, 0, stream>>>(x, out, tail_start, n);
    }
}